// Round 6
// baseline (185.458 us; speedup 1.0000x reference)
//
#include <hip/hip_runtime.h>
#include <hip/hip_bf16.h>
#include <math.h>

// CrossGeometricStructureEmbedding, round 6.
// R5 post-mortem: MFMA pipe already at its 28us floor; VALU (duplicated
// __sincosf fill) was the top pipe at 52us. R6: 512-thread blocks (8 waves x
// 32 cols = all 256 cols, fill ONCE per point-type), fast hw sincos
// (v_sin/v_cos on revolutions, 1/2pi folded into the frequency constant),
// B streamed from L2 (W L2-resident), 16 double-buffered phases (8 pts x
// {d,a}) with fill(p+1) fused into phase p's ks-loop. One barrier per phase.
// Conflict-clean LDS: row stride 264 shorts; fill row=lane, wave owns 4 chunk
// columns -> both b128 writes and A-frag reads at structural-min 8 phases.
// Grid = 512 blocks = exactly 2 resident/CU (16 waves, ~50% occupancy).

typedef __attribute__((ext_vector_type(8))) short short8;
typedef __attribute__((ext_vector_type(4))) float f32x4;
typedef __attribute__((ext_vector_type(4))) unsigned int uint4v;

#define HH 256
#define STR 264      // shorts per E row (+8 pad: rotates banks by 4/row)
#define P_PTS 8
#define NPTS 4096

__device__ __forceinline__ unsigned short f2bf(float f) {
    union { float f; unsigned int u; } v; v.f = f;
    unsigned int r = v.u + 0x7fffu + ((v.u >> 16) & 1u);  // RNE
    return (unsigned short)(r >> 16);
}

__device__ __forceinline__ unsigned int pack_sc(float s, float c) {
    union { __hip_bfloat162 h; unsigned int u; } v;
    v.h = __float22bfloat162_rn(make_float2(s, c));  // low = sin, high = cos
    return v.u;
}

__global__ __launch_bounds__(256)
void prep_w_kernel(const float* __restrict__ Wa, const float* __restrict__ Wd,
                   unsigned short* __restrict__ wbf) {
    int i = blockIdx.x * 256 + threadIdx.x;
    if (i < HH * HH) {
        wbf[i] = f2bf(Wd[i]);             // [0, 65536): Wd bf16
        wbf[HH * HH + i] = f2bf(Wa[i]);   // [65536, 131072): Wa bf16
    }
}

__global__ __launch_bounds__(512, 4)
void cgse_main(const float* __restrict__ points,
               const float* __restrict__ anchors,
               const unsigned short* __restrict__ wbf,
               const float* __restrict__ ba,
               const float* __restrict__ bd,
               float* __restrict__ out) {
    __shared__ __align__(16) unsigned short E[2][64 * STR];  // 67.6 KB dbuf
    __shared__ float xsd[2][64], xsa[2][64];
    __shared__ float anch[192];

    const int tid = threadIdx.x;
    const int wave = tid >> 6, lane = tid & 63;
    const int quad = lane >> 4, l16 = lane & 15;
    const int base = blockIdx.x * P_PTS;

    // wave frequency base: 1e4^(-wave/8) * (1/2pi)  (omega in REVOLUTIONS)
    const float cw = __expf(-(float)wave * 1.1512925464970228f)
                     * 0.15915494309189535f;
    // chunk-local frequency constants (compile-time per unrolled c):
    // dt4[c] = 1e4^(-c/32); within a chunk, ratios r^j, r = 1e4^(-1/128).
    const float DT4[4] = {1.0f, 0.7498942093324559f, 0.5623413251903491f,
                          0.4216965034285822f};
    const float R1 = 0.9305720409297085f;
    const float R2 = 0.8659643233600653f;
    const float R3 = 0.8058421877614819f;

    float bias[2];
    #pragma unroll
    for (int nt = 0; nt < 2; ++nt) {
        const int c = wave * 32 + nt * 16 + l16;
        bias[nt] = ba[c] + bd[c];
    }

    if (tid < 192) anch[tid] = anchors[tid];
    __syncthreads();

    auto geom = [&](int pn, int slot) {
        if (tid < 64) {  // wave 0, wave-uniform branch
            const float px = points[pn * 3 + 0], py = points[pn * 3 + 1], pz = points[pn * 3 + 2];
            const int k = tid, k2 = (tid + 1) & 63;  // roll(-1)
            const float r1x = px - anch[k * 3 + 0];
            const float r1y = py - anch[k * 3 + 1];
            const float r1z = pz - anch[k * 3 + 2];
            const float r2x = px - anch[k2 * 3 + 0];
            const float r2y = py - anch[k2 * 3 + 1];
            const float r2z = pz - anch[k2 * 3 + 2];
            xsd[slot][k] = sqrtf(r1x * r1x + r1y * r1y + r1z * r1z) * 5.0f;  // /SIGMA_D
            const float cx = r1y * r2z - r1z * r2y;
            const float cy = r1z * r2x - r1x * r2z;
            const float cz = r1x * r2y - r1y * r2x;
            const float sv = sqrtf(cx * cx + cy * cy + cz * cz);
            const float cv = r1x * r2x + r1y * r2y + r1z * r2z;
            xsa[slot][k] = atan2f(sv, cv) * 3.8197186342054885f;  // *180/(15*pi)
        }
    };

    // fill one 16B chunk: row = lane, chunk col = 4*wave + c (c compile-time)
    auto fill_chunk = [&](unsigned short* Eb, int c, float xr) {
        const float t0 = xr * DT4[c];
        float t[4] = {t0, t0 * R1, t0 * R2, t0 * R3};
        uint4v w;
        #pragma unroll
        for (int j = 0; j < 4; ++j) {
            float f = t[j] - floorf(t[j]);                  // revolutions
            w[j] = pack_sc(__builtin_amdgcn_sinf(f), __builtin_amdgcn_cosf(f));
        }
        *(uint4v*)&Eb[lane * STR + (4 * wave + c) * 8] = w;
    };

    geom(base + 0, 0);
    __syncthreads();  // xs*[0] ready

    // prologue: fill buf0 for phase 0 (point 0, d-type)
    {
        const float xr = xsd[0][lane] * cw;
        #pragma unroll
        for (int c = 0; c < 4; ++c) fill_chunk(E[0], c, xr);
    }

    float dmx[2];
    for (int ph = 0; ph < 2 * P_PTS; ++ph) {
        __syncthreads();  // buf(ph&1) filled; xs for phase ph+1 ready
        const int q = ph >> 1, type = ph & 1;
        const unsigned short* Ecur = E[ph & 1];
        unsigned short* Enxt = E[(ph & 1) ^ 1];

        const bool dofill = (ph + 1) < 2 * P_PTS;
        float xr = 0.f;
        if (dofill) {
            const int pn = (ph + 1) >> 1, tn = (ph + 1) & 1;
            xr = (tn ? xsa[pn & 1][lane] : xsd[pn & 1][lane]) * cw;
        }
        if (type == 0 && q + 1 < P_PTS) geom(base + q + 1, (q + 1) & 1);

        const unsigned short* wb = wbf + type * (HH * HH)
                                   + (wave * 32 + l16) * HH + quad * 8;

        f32x4 acc[4][2];
        #pragma unroll
        for (int mt = 0; mt < 4; ++mt)
            #pragma unroll
            for (int nt = 0; nt < 2; ++nt)
                acc[mt][nt] = (f32x4){0.f, 0.f, 0.f, 0.f};

        #pragma unroll
        for (int ks = 0; ks < 8; ++ks) {
            if (dofill && ks < 4) fill_chunk(Enxt, ks, xr);  // fused fill(p+1)
            const short8 b0 = *(const short8*)(wb + ks * 32);
            const short8 b1 = *(const short8*)(wb + 16 * HH + ks * 32);
            #pragma unroll
            for (int mt = 0; mt < 4; ++mt) {
                const short8 afr = *(const short8*)
                    &Ecur[(mt * 16 + l16) * STR + ks * 32 + quad * 8];
                acc[mt][0] = __builtin_amdgcn_mfma_f32_16x16x32_bf16(afr, b0, acc[mt][0], 0, 0, 0);
                acc[mt][1] = __builtin_amdgcn_mfma_f32_16x16x32_bf16(afr, b1, acc[mt][1], 0, 0, 0);
            }
        }

        #pragma unroll
        for (int nt = 0; nt < 2; ++nt) {
            float m = fmaxf(fmaxf(acc[0][nt][0], acc[0][nt][1]),
                            fmaxf(acc[0][nt][2], acc[0][nt][3]));
            #pragma unroll
            for (int mt = 1; mt < 4; ++mt)
                m = fmaxf(m, fmaxf(fmaxf(acc[mt][nt][0], acc[mt][nt][1]),
                                   fmaxf(acc[mt][nt][2], acc[mt][nt][3])));
            m = fmaxf(m, __shfl_down(m, 32));
            m = fmaxf(m, __shfl_down(m, 16));  // lanes 0..15: max over 64 anchors
            if (type == 0) {
                dmx[nt] = m;
            } else if (lane < 16) {
                out[(base + q) * HH + wave * 32 + nt * 16 + l16] =
                    dmx[nt] + m + bias[nt];
            }
        }
    }
}

extern "C" void kernel_launch(void* const* d_in, const int* in_sizes, int n_in,
                              void* d_out, int out_size, void* d_ws, size_t ws_size,
                              hipStream_t stream) {
    const float* points  = (const float*)d_in[0];
    const float* anchors = (const float*)d_in[1];
    // d_in[2] = cor_score: unused by the reference
    const float* Wa = (const float*)d_in[3];
    const float* ba = (const float*)d_in[4];
    const float* Wd = (const float*)d_in[5];
    const float* bd = (const float*)d_in[6];

    unsigned short* wbf = (unsigned short*)d_ws;  // 256 KB: Wd|Wa bf16

    hipLaunchKernelGGL(prep_w_kernel, dim3(256), dim3(256), 0, stream, Wa, Wd, wbf);
    hipLaunchKernelGGL(cgse_main, dim3(NPTS / P_PTS), dim3(512), 0, stream,
                       points, anchors, wbf, ba, bd, (float*)d_out);
}

// Round 7
// 130.548 us; speedup vs baseline: 1.4206x; 1.4206x over previous
//
#include <hip/hip_runtime.h>
#include <hip/hip_bf16.h>
#include <math.h>

// CrossGeometricStructureEmbedding, round 7.
// R6 post-mortem: streaming B from L2 in the ks-loop = latency-bound (all
// pipes <26%). W register-residency is the load-bearing feature of every good
// round. R7: one W type in regs at a time (128 VGPR strip), block does a
// d-pass over 8 points (max -> dms[] in LDS), reloads W, then an a-pass
// (out = amx + dms + bias). 32x32x16 MFMA (2382 vs 2075 TF ubench, floor
// 33->27us). Fast revolution sincos (R6-validated). Xor-swizzled dbuf E
// (R5: halves conflicts), fill(ph+1) fused into gemm(ph), 1 barrier/phase.
// VGPR demand ~230 under (256,2)=256 cap -> no spill. LDS 78.6KB, grid 512
// = 2 blocks/CU; cross-block overlap hides within-block fill/gemm phases.

typedef __attribute__((ext_vector_type(8))) short short8;
typedef __attribute__((ext_vector_type(16))) float f32x16;
typedef __attribute__((ext_vector_type(4))) unsigned int uint4v;

#define HH 256
#define P_PTS 8
#define NPTS 4096

__device__ __forceinline__ unsigned short f2bf(float f) {
    union { float f; unsigned int u; } v; v.f = f;
    unsigned int r = v.u + 0x7fffu + ((v.u >> 16) & 1u);  // RNE
    return (unsigned short)(r >> 16);
}

__device__ __forceinline__ unsigned int pack_sc(float s, float c) {
    union { __hip_bfloat162 h; unsigned int u; } v;
    v.h = __float22bfloat162_rn(make_float2(s, c));  // low = sin, high = cos
    return v.u;
}

__global__ __launch_bounds__(256)
void prep_w_kernel(const float* __restrict__ Wa, const float* __restrict__ Wd,
                   unsigned short* __restrict__ wbf) {
    int i = blockIdx.x * 256 + threadIdx.x;
    if (i < HH * HH) {
        wbf[i] = f2bf(Wd[i]);             // [0, 65536): Wd bf16
        wbf[HH * HH + i] = f2bf(Wa[i]);   // [65536, 131072): Wa bf16
    }
}

// E chunk addressing: 16B chunks (8 shorts), 32 per 256-short row.
// chunk ch of row r lives at shorts offset r*256 + ((ch ^ (r&7)) << 3).
__device__ __forceinline__ int eoff(int r, int ch) {
    return r * HH + (((ch ^ (r & 7)) & 31) << 3);
}

__global__ __launch_bounds__(256, 2)
void cgse_main(const float* __restrict__ points,
               const float* __restrict__ anchors,
               const unsigned short* __restrict__ wbf,
               const float* __restrict__ ba,
               const float* __restrict__ bd,
               float* __restrict__ out) {
    __shared__ __align__(16) unsigned short E[2][64 * HH];  // 64 KB dbuf
    __shared__ float dms[P_PTS][HH];                        // 8 KB d-pass maxes
    __shared__ float xsd[P_PTS][64], xsa[P_PTS][64];        // 4 KB
    __shared__ float anch[192];

    const int tid = threadIdx.x;
    const int wave = tid >> 6, lane = tid & 63;
    const int l5 = lane & 31, half = lane >> 5;
    const int base = blockIdx.x * P_PTS;

    // ---- anchors, then geometry for all 8 points (512 tasks / 256 threads)
    if (tid < 192) anch[tid] = anchors[tid];
    __syncthreads();
    #pragma unroll
    for (int rep = 0; rep < 2; ++rep) {
        const int task = rep * 256 + tid;
        const int pt = task >> 6, k = task & 63, k2 = (k + 1) & 63;
        const int pn = base + pt;
        const float px = points[pn * 3 + 0], py = points[pn * 3 + 1], pz = points[pn * 3 + 2];
        const float r1x = px - anch[k * 3 + 0];
        const float r1y = py - anch[k * 3 + 1];
        const float r1z = pz - anch[k * 3 + 2];
        const float r2x = px - anch[k2 * 3 + 0];
        const float r2y = py - anch[k2 * 3 + 1];
        const float r2z = pz - anch[k2 * 3 + 2];
        xsd[pt][k] = sqrtf(r1x * r1x + r1y * r1y + r1z * r1z) * 5.0f;  // /SIGMA_D
        const float cx = r1y * r2z - r1z * r2y;
        const float cy = r1z * r2x - r1x * r2z;
        const float cz = r1x * r2y - r1y * r2x;
        const float sv = sqrtf(cx * cx + cy * cy + cz * cz);
        const float cv = r1x * r2x + r1y * r2y + r1z * r2z;
        xsa[pt][k] = atan2f(sv, cv) * 3.8197186342054885f;  // *180/(15*pi)
    }

    float bias[2];
    #pragma unroll
    for (int nt = 0; nt < 2; ++nt) {
        const int c = wave * 64 + nt * 32 + l5;
        bias[nt] = ba[c] + bd[c];
    }

    // ---- fill constants: omega_i = x * rho^i / 2pi, rho = 1e4^(-1/128).
    // rho^32 = 0.1 -> per-wave base cw = (1/2pi) * 10^-wave.
    // chunk ch = 8*wave + c covers pairs i = 4ch..4ch+3: DC[c] = 10^(-c/8),
    // within-chunk ratios 10^(-j/32).
    const float cw = 0.15915494309189535f * __expf(-(float)wave * 2.302585092994046f);
    const float DC[8] = {1.0f, 0.7498942093324559f, 0.5623413251903491f,
                         0.4216965034285822f, 0.31622776601683794f,
                         0.23713737056616552f, 0.1778279410038923f,
                         0.13335214321633242f};

    // fill one 16B chunk: row = lane, chunk col = 8*wave + c (c compile-time)
    auto fill_chunk = [&](unsigned short* Eb, int c, float xr) {
        const float t0 = xr * DC[c];
        const float t[4] = {t0, t0 * 0.9305720409297085f,
                            t0 * 0.8659643233600653f, t0 * 0.8058421877614819f};
        uint4v w;
        #pragma unroll
        for (int j = 0; j < 4; ++j) {
            const float f = t[j] - floorf(t[j]);  // revolutions
            w[j] = pack_sc(__builtin_amdgcn_sinf(f), __builtin_amdgcn_cosf(f));
        }
        *(uint4v*)&Eb[eoff(lane, 8 * wave + c)] = w;
    };

    // ---- W strip (one type) in registers: 2 nt x 16 ks x short8 = 128 VGPRs
    short8 bw[2][16];
    auto loadW = [&](int t) {
        const unsigned short* wp = wbf + t * (HH * HH);
        #pragma unroll
        for (int nt = 0; nt < 2; ++nt) {
            const unsigned short* wr = wp + (wave * 64 + nt * 32 + l5) * HH + half * 8;
            #pragma unroll
            for (int ks = 0; ks < 16; ++ks)
                bw[nt][ks] = *(const short8*)(wr + ks * 16);
        }
    };

    loadW(0);
    __syncthreads();  // xsd/xsa ready
    // prologue: fill buf0 for phase 0 (point 0, d-type)
    {
        const float xr = xsd[0][lane] * cw;
        #pragma unroll
        for (int c = 0; c < 8; ++c) fill_chunk(E[0], c, xr);
    }

    // 16 phases: 0..7 = d-pass (pt 0..7), 8..15 = a-pass (pt 0..7)
    #pragma unroll 1
    for (int ph = 0; ph < 16; ++ph) {
        __syncthreads();  // E[ph&1] filled; E[ph&1 ^1] free
        const int b = ph & 1;
        if (ph == 8) loadW(1);  // switch to Wa for the a-pass

        const bool dofill = (ph + 1) < 16;
        float xr = 0.f;
        if (dofill) {
            const int pn = (ph + 1) & 7;
            xr = ((ph + 1) < 8 ? xsd[pn][lane] : xsa[pn][lane]) * cw;
        }

        f32x16 acc[2][2];
        #pragma unroll
        for (int mt = 0; mt < 2; ++mt)
            #pragma unroll
            for (int nt = 0; nt < 2; ++nt)
                #pragma unroll
                for (int r = 0; r < 16; ++r) acc[mt][nt][r] = 0.f;

        #pragma unroll
        for (int ks = 0; ks < 16; ++ks) {
            if (dofill && (ks & 1) == 0) fill_chunk(E[b ^ 1], ks >> 1, xr);
            #pragma unroll
            for (int mt = 0; mt < 2; ++mt) {
                const short8 afr = *(const short8*)
                    &E[b][eoff(mt * 32 + l5, 2 * ks + half)];
                acc[mt][0] = __builtin_amdgcn_mfma_f32_32x32x16_bf16(
                    afr, bw[0][ks], acc[mt][0], 0, 0, 0);
                acc[mt][1] = __builtin_amdgcn_mfma_f32_32x32x16_bf16(
                    afr, bw[1][ks], acc[mt][1], 0, 0, 0);
            }
        }

        // epilogue: max over 64 anchors. Per lane, the 2x16 acc regs cover 32
        // of the 64 rows (C layout: col=lane&31, rows split by lane-half);
        // one shfl_down(32) merges the halves. Valid on lanes 0..31.
        const int q = ph & 7;
        #pragma unroll
        for (int nt = 0; nt < 2; ++nt) {
            float m = acc[0][nt][0];
            #pragma unroll
            for (int r = 1; r < 16; ++r) m = fmaxf(m, acc[0][nt][r]);
            #pragma unroll
            for (int r = 0; r < 16; ++r) m = fmaxf(m, acc[1][nt][r]);
            m = fmaxf(m, __shfl_down(m, 32));
            if (lane < 32) {
                const int col = wave * 64 + nt * 32 + l5;
                if (ph < 8) dms[q][col] = m;
                else out[(base + q) * HH + col] = m + dms[q][col] + bias[nt];
            }
        }
    }
}

extern "C" void kernel_launch(void* const* d_in, const int* in_sizes, int n_in,
                              void* d_out, int out_size, void* d_ws, size_t ws_size,
                              hipStream_t stream) {
    const float* points  = (const float*)d_in[0];
    const float* anchors = (const float*)d_in[1];
    // d_in[2] = cor_score: unused by the reference
    const float* Wa = (const float*)d_in[3];
    const float* ba = (const float*)d_in[4];
    const float* Wd = (const float*)d_in[5];
    const float* bd = (const float*)d_in[6];

    unsigned short* wbf = (unsigned short*)d_ws;  // 256 KB: Wd|Wa bf16

    hipLaunchKernelGGL(prep_w_kernel, dim3(256), dim3(256), 0, stream, Wa, Wd, wbf);
    hipLaunchKernelGGL(cgse_main, dim3(NPTS / P_PTS), dim3(256), 0, stream,
                       points, anchors, wbf, ba, bd, (float*)d_out);
}